// Round 3
// baseline (866.555 us; speedup 1.0000x reference)
//
#include <hip/hip_runtime.h>

// SSIM loss v3: wave-autonomous row-streaming. No __syncthreads in the hot
// path, ~2KB LDS, 11-row x 5-quantity register ring for the vertical conv.
// Each wave: 54 output cols (lanes 5..58 of a 64-col load window), streams a
// 64-output-row chunk. Grid = 10 strips x 8 chunks x 48 planes = 3840 waves.

#define BATCH  16
#define CHAN   3
#define H_     512
#define W_     512
#define HW     (H_ * W_)
#define SPAN   54        // output cols per strip
#define NSTRIP 10        // ceil(512/54)
#define NCHUNK 8
#define CH_H   64        // output rows per chunk
#define WAVES_TOTAL (NSTRIP * NCHUNK * BATCH * CHAN)   // 3840
#define STW    144       // per-wave LDS dwords (needs >=133, 16B-aligned)

// Normalized 11-tap Gaussian, sigma=1.5 (same constants that gave absmax 0).
#define GW0 0.0010284f
#define GW1 0.0075988f
#define GW2 0.0360008f
#define GW3 0.1093554f
#define GW4 0.2130056f
#define GW5 0.2660117f

__device__ __forceinline__ float ssim_loss_px(float mu1, float mu2,
                                              float x11, float x22, float x12) {
    const float c1 = 1.0e-4f;
    const float c2 = 9.0e-4f;
    float mu1s = mu1 * mu1;
    float mu2s = mu2 * mu2;
    float m12  = mu1 * mu2;
    float s1v  = x11 - mu1s;
    float s2v  = x22 - mu2s;
    float s12  = x12 - m12;
    float num  = (2.0f * m12 + c1) * (2.0f * s12 + c2);
    float den  = (mu1s + mu2s + c1) * (s1v + s2v + c2);
    float l = 1.0f - num / den;
    return fminf(fmaxf(l, 0.0f), 1.0f);
}

__global__ __launch_bounds__(256, 4) void ssim_kernel(const float* __restrict__ img1,
                                                      const float* __restrict__ img2,
                                                      float* __restrict__ out) {
    __shared__ __align__(16) float stage[4][STW];  // per-wave row staging
    __shared__ float wsum[4];

    const float wgt[11] = {GW0, GW1, GW2, GW3, GW4, GW5, GW4, GW3, GW2, GW1, GW0};

    const int tid  = threadIdx.x;
    const int lane = tid & 63;
    const int wv   = tid >> 6;

    const int wid   = blockIdx.x * 4 + wv;            // 0..3839
    const int plane = wid / (NSTRIP * NCHUNK);
    const int rem   = wid - plane * (NSTRIP * NCHUNK);
    const int strip = rem % NSTRIP;
    const int chunk = rem / NSTRIP;
    const int y0 = chunk * CH_H;
    const int c0 = strip * SPAN;                      // first output col

    const int  colg  = c0 - 5 + lane;                 // col this lane loads
    const bool colOk = (unsigned)colg < (unsigned)W_;
    const int  colC  = colOk ? colg : 0;

    const float* __restrict__ p1 = img1 + (size_t)plane * HW + colC;
    const float* __restrict__ p2 = img2 + (size_t)plane * HW + colC;

    float* st = &stage[wv][0];
    const int rdbase = (lane >= 5) ? (lane - 5) : 0;  // clamped; lanes 0..4/59..63 discarded

    const int  outCol    = c0 + lane - 5;
    const bool laneValid = (lane >= 5) && (lane <= 58) && (outCol < W_);

    float ring[11][5];

    // One streamed row: load (guarded) -> stage in LDS -> h-conv 5 quantities.
    auto do_row = [&](int r, float* dst) {
        float v1 = 0.0f, v2 = 0.0f;
        if ((unsigned)r < (unsigned)H_) {             // wave-uniform branch
            size_t off = (size_t)r * W_;
            v1 = p1[off];
            v2 = p2[off];
            if (!colOk) { v1 = 0.0f; v2 = 0.0f; }
        }
        st[lane]      = v1;
        st[lane + 64] = v2;
        float m1 = 0, m2 = 0, m11 = 0, m22 = 0, m12 = 0;
#pragma unroll
        for (int k = 0; k < 11; ++k) {
            float a  = st[rdbase + k];
            float b  = st[rdbase + k + 64];
            float t1 = wgt[k] * a;
            float t2 = wgt[k] * b;
            m1  += t1;
            m2  += t2;
            m11 = fmaf(t1, a, m11);
            m22 = fmaf(t2, b, m22);
            m12 = fmaf(t1, b, m12);
        }
        dst[0] = m1; dst[1] = m2; dst[2] = m11; dst[3] = m22; dst[4] = m12;
    };

    // Prime ring with h-rows y0-5 .. y0+4 (slots 0..9).
#pragma unroll
    for (int i = 0; i < 10; ++i) do_row(y0 - 5 + i, ring[i]);

    float acc = 0.0f;

    // Main: 6 x 11 fully unrolled steps; output yy = 11t+u (mask yy>=64).
#pragma unroll
    for (int t = 0; t < 6; ++t) {
#pragma unroll
        for (int u = 0; u < 11; ++u) {
            const int yy = 11 * t + u;
            if (yy < CH_H) {
                do_row(y0 + yy + 5, ring[(u + 10) % 11]);   // newest h-row
                float V0 = 0, V1 = 0, V2 = 0, V3 = 0, V4 = 0;
#pragma unroll
                for (int j = 0; j < 11; ++j) {
                    const float wj = wgt[j];
                    const float* hr = ring[(u + j) % 11];
                    V0 = fmaf(wj, hr[0], V0);
                    V1 = fmaf(wj, hr[1], V1);
                    V2 = fmaf(wj, hr[2], V2);
                    V3 = fmaf(wj, hr[3], V3);
                    V4 = fmaf(wj, hr[4], V4);
                }
                float loss = ssim_loss_px(V0, V1, V2, V3, V4);
                acc += laneValid ? loss : 0.0f;
            }
        }
    }

    // Reduction: wave shuffle -> LDS -> one atomic per block.
#pragma unroll
    for (int off = 32; off > 0; off >>= 1) acc += __shfl_down(acc, off);
    if (lane == 0) wsum[wv] = acc;
    __syncthreads();
    if (tid == 0) {
        float bs = wsum[0] + wsum[1] + wsum[2] + wsum[3];
        atomicAdd(out, bs * (0.5f / (float)((long)BATCH * CHAN * H_ * W_)));
    }
}

extern "C" void kernel_launch(void* const* d_in, const int* in_sizes, int n_in,
                              void* d_out, int out_size, void* d_ws, size_t ws_size,
                              hipStream_t stream) {
    const float* img1 = (const float*)d_in[0];
    const float* img2 = (const float*)d_in[1];
    float* out = (float*)d_out;

    hipMemsetAsync(out, 0, sizeof(float), stream);

    ssim_kernel<<<dim3(WAVES_TOTAL / 4), 256, 0, stream>>>(img1, img2, out);
}

// Round 5
// 800.360 us; speedup vs baseline: 1.0827x; 1.0827x over previous
//
#include <hip/hip_runtime.h>

// SSIM loss v5: v4's row-streaming + 11-slot accumulator structure, with the
// LDS staging made wave-synchronous-SAFE via volatile accesses. v4 failed
// because without a barrier the compiler may hoist/CSE st[lane+k] reads
// (per-thread alias analysis says they never alias this thread's writes).
// volatile forces every staged read/write to be issued in program order;
// same-wave DS ops execute in order in the LDS pipe, so no barrier needed.

#define BATCH  16
#define CHAN   3
#define H_     512
#define W_     512
#define HW     (H_ * W_)
#define NSTRIP 8
#define NCHUNK 8
#define CH_H   64
#define NPIX   ((long)BATCH*CHAN*H_*W_)

// Normalized 11-tap Gaussian, sigma=1.5 (constants gave absmax 0 in v1/v2).
#define GW0 0.0010284f
#define GW1 0.0075988f
#define GW2 0.0360008f
#define GW3 0.1093554f
#define GW4 0.2130056f
#define GW5 0.2660117f

__device__ __forceinline__ float wg(int k) {  // k literal after unroll -> folds
    return (k == 0 || k == 10) ? GW0
         : (k == 1 || k == 9)  ? GW1
         : (k == 2 || k == 8)  ? GW2
         : (k == 3 || k == 7)  ? GW3
         : (k == 4 || k == 6)  ? GW4 : GW5;
}

struct HR { float m1, m2, m11, m22, m12; };

__device__ __forceinline__ float ssim_retire(float mu1, float mu2,
                                             float x11, float x22, float x12) {
    const float c1 = 1.0e-4f;
    const float c2 = 9.0e-4f;
    float mu1s = mu1 * mu1;
    float mu2s = mu2 * mu2;
    float m12  = mu1 * mu2;
    float num  = (2.0f * m12 + c1) * (2.0f * (x12 - m12) + c2);
    float den  = (mu1s + mu2s + c1) * ((x11 - mu1s) + (x22 - mu2s) + c2);
    float l = 1.0f - num / den;
    return fminf(fmaxf(l, 0.0f), 1.0f);
}

// Accumulate h-row into slot S (S folds to a literal after unroll).
#define ACC5(S, WJ, H)                                   \
    a0[S] = fmaf((WJ), (H).m1,  a0[S]);                  \
    a1[S] = fmaf((WJ), (H).m2,  a1[S]);                  \
    a2[S] = fmaf((WJ), (H).m11, a2[S]);                  \
    a3[S] = fmaf((WJ), (H).m22, a3[S]);                  \
    a4[S] = fmaf((WJ), (H).m12, a4[S]);

// Prologue step I = 0..9: h-row r = y0-5+I; outputs o = 0..I (j = 10-I..10,
// o = j-(10-I)), weight wg(10-j), slot (5+o)%11 = (I+6+j)%11.
#define PSTEP(I) do {                                                  \
    int r_ = y0 - 5 + (I);                                             \
    if ((unsigned)r_ < (unsigned)H_) {                                 \
        HR h_ = row_step(r_);                                          \
        _Pragma("unroll")                                              \
        for (int j = 10 - (I); j < 11; ++j) {                          \
            const int s_ = ((I) + 6 + j) % 11;                         \
            ACC5(s_, wg(10 - j), h_)                                   \
        }                                                              \
    }                                                                  \
} while (0)

// Steady step: output row yy = 11*t + U retires. New h-row r = y0+5+yy
// contributes to outputs yy+j (j=0..10), tap weight wg(10-j), slot (5+U+j)%11.
#define SSTEP(U) do {                                                  \
    int yy_ = 11 * t + (U);                                            \
    int r_ = y0 + 5 + yy_;                                             \
    if ((unsigned)r_ < (unsigned)H_) {                                 \
        HR h_ = row_step(r_);                                          \
        _Pragma("unroll")                                              \
        for (int j = 0; j < 11; ++j) {                                 \
            const int s_ = (5 + (U) + j) % 11;                         \
            ACC5(s_, wg(10 - j), h_)                                   \
        }                                                              \
    }                                                                  \
    {                                                                  \
        const int s0_ = (5 + (U)) % 11;                                \
        lsum += ssim_retire(a0[s0_], a1[s0_], a2[s0_], a3[s0_], a4[s0_]); \
        a0[s0_] = 0.f; a1[s0_] = 0.f; a2[s0_] = 0.f;                   \
        a3[s0_] = 0.f; a4[s0_] = 0.f;                                  \
    }                                                                  \
} while (0)

__global__ __launch_bounds__(256, 3) void ssim_kernel(const float* __restrict__ img1,
                                                      const float* __restrict__ img2,
                                                      float* __restrict__ out) {
    __shared__ __align__(16) float stage[4][160];   // 150 floats used per wave
    __shared__ float wsum[4];

    const int tid  = threadIdx.x;
    const int lane = tid & 63;
    const int wv   = tid >> 6;

    const int wid   = blockIdx.x * 4 + wv;           // 0..3071
    const int plane = wid >> 6;                      // / (NSTRIP*NCHUNK)
    const int rem   = wid & 63;
    const int strip = rem & 7;
    const int chunk = rem >> 3;
    const int y0 = chunk * CH_H;
    const int c0 = strip * 64;

    // st float index 2*i   <-> img1 col c0-5+i
    // st float index 2*i+1 <-> img2 col c0-5+i       (i = 0..74)
    const int  colg  = c0 - 5 + lane;                // only <0 can be OOB here
    const bool colOk = (colg >= 0);
    const int  colC  = colOk ? colg : 0;
    const int  colg2  = c0 + 59 + lane;              // halo cols, lanes 0..10
    const bool colOk2 = (lane < 11) && (colg2 < W_);
    const int  col2C  = colOk2 ? colg2 : 0;

    const size_t pb = (size_t)plane * HW;
    const float* __restrict__ p1  = img1 + pb + colC;
    const float* __restrict__ p2  = img2 + pb + colC;
    const float* __restrict__ p1b = img1 + pb + col2C;
    const float* __restrict__ p2b = img2 + pb + col2C;

    volatile float* st = (volatile float*)stage[wv];

    // Load row r, stage 75 col-pairs, horizontal 11-tap for col c0+lane.
    auto row_step = [&](int r) -> HR {
        size_t off = (size_t)r * W_;
        float v1 = colOk ? p1[off] : 0.0f;
        float v2 = colOk ? p2[off] : 0.0f;
        st[2 * lane]     = v1;
        st[2 * lane + 1] = v2;
        if (lane < 11) {
            st[2 * (64 + lane)]     = colOk2 ? p1b[off] : 0.0f;
            st[2 * (64 + lane) + 1] = colOk2 ? p2b[off] : 0.0f;
        }
        HR h; h.m1 = 0.f; h.m2 = 0.f; h.m11 = 0.f; h.m22 = 0.f; h.m12 = 0.f;
#pragma unroll
        for (int k = 0; k < 11; ++k) {
            float a = st[2 * (lane + k)];
            float b = st[2 * (lane + k) + 1];
            float wk = wg(k);
            float t1 = wk * a;
            float t2 = wk * b;
            h.m1  += t1;
            h.m2  += t2;
            h.m11 = fmaf(t1, a, h.m11);
            h.m22 = fmaf(t2, b, h.m22);
            h.m12 = fmaf(t1, b, h.m12);
        }
        return h;
    };

    float a0[11], a1[11], a2[11], a3[11], a4[11];
#pragma unroll
    for (int s = 0; s < 11; ++s) {
        a0[s] = 0.f; a1[s] = 0.f; a2[s] = 0.f; a3[s] = 0.f; a4[s] = 0.f;
    }

    float lsum = 0.0f;

    // Prologue: h-rows y0-5 .. y0+4.
    PSTEP(0); PSTEP(1); PSTEP(2); PSTEP(3); PSTEP(4);
    PSTEP(5); PSTEP(6); PSTEP(7); PSTEP(8); PSTEP(9);

    // Steady: 5 full 11-phase cycles (outputs 0..54) + 9-phase tail (55..63).
    for (int t = 0; t < 5; ++t) {
        SSTEP(0); SSTEP(1); SSTEP(2); SSTEP(3); SSTEP(4); SSTEP(5);
        SSTEP(6); SSTEP(7); SSTEP(8); SSTEP(9); SSTEP(10);
    }
    {
        const int t = 5;
        SSTEP(0); SSTEP(1); SSTEP(2); SSTEP(3); SSTEP(4);
        SSTEP(5); SSTEP(6); SSTEP(7); SSTEP(8);
    }

    // Reduction: wave shuffle -> LDS -> one atomic per block.
#pragma unroll
    for (int off = 32; off > 0; off >>= 1) lsum += __shfl_down(lsum, off);
    if (lane == 0) wsum[wv] = lsum;
    __syncthreads();
    if (tid == 0) {
        float bs = wsum[0] + wsum[1] + wsum[2] + wsum[3];
        atomicAdd(out, bs * (0.5f / (float)NPIX));
    }
}

extern "C" void kernel_launch(void* const* d_in, const int* in_sizes, int n_in,
                              void* d_out, int out_size, void* d_ws, size_t ws_size,
                              hipStream_t stream) {
    const float* img1 = (const float*)d_in[0];
    const float* img2 = (const float*)d_in[1];
    float* out = (float*)d_out;

    hipMemsetAsync(out, 0, sizeof(float), stream);

    ssim_kernel<<<dim3(NSTRIP * NCHUNK * BATCH * CHAN / 4), 256, 0, stream>>>(img1, img2, out);
}

// Round 6
// 161.609 us; speedup vs baseline: 5.3621x; 4.9525x over previous
//
#include <hip/hip_runtime.h>

// SSIM loss v6: row-streaming with a 55-NAMED-SCALAR shift register.
// v3/v5 put the 11-slot accumulator state in private arrays -> SROA failed ->
// scratch spill (1.7GB HBM traffic, 800us). Named scalars are SSA values;
// mem2reg cannot fail. Uniform pipeline step (h-row r = y0+yy+5):
//   stage row -> prefetch row r+1 -> h-conv -> ACC into slots 0..10 with
//   weight w[10-i] -> retire slot 0 (output row yy) -> shift slots down.
// LDS: two stride-1 float arrays (2-way bank alias = free), non-volatile,
// fenced with asm memory clobbers (prevents the v4 hoist/CSE bug; same-wave
// DS ops execute in order in HW). Grid: 8 strips x 8 chunks x 48 planes =
// 3072 waves = 768 blocks = exactly 3 blocks/CU.

#define BATCH  16
#define CHAN   3
#define H_     512
#define W_     512
#define HW     (H_ * W_)
#define CH_H   64
#define NPIX   ((long)BATCH*CHAN*H_*W_)

// Normalized 11-tap Gaussian, sigma=1.5 (constants gave absmax 0 in v1/v2/v5).
#define GW0 0.0010284f
#define GW1 0.0075988f
#define GW2 0.0360008f
#define GW3 0.1093554f
#define GW4 0.2130056f
#define GW5 0.2660117f

__device__ __forceinline__ float wg(int k) {  // k literal -> folds to constant
    return (k == 0 || k == 10) ? GW0
         : (k == 1 || k == 9)  ? GW1
         : (k == 2 || k == 8)  ? GW2
         : (k == 3 || k == 7)  ? GW3
         : (k == 4 || k == 6)  ? GW4 : GW5;
}

__device__ __forceinline__ float ssim_retire(float mu1, float mu2,
                                             float x11, float x22, float x12) {
    const float c1 = 1.0e-4f;
    const float c2 = 9.0e-4f;
    float mu1s = mu1 * mu1;
    float mu2s = mu2 * mu2;
    float m12  = mu1 * mu2;
    float num  = (2.0f * m12 + c1) * (2.0f * (x12 - m12) + c2);
    float den  = (mu1s + mu2s + c1) * ((x11 - mu1s) + (x22 - mu2s) + c2);
    float l = 1.0f - num / den;
    return fminf(fmaxf(l, 0.0f), 1.0f);
}

// 55 named accumulator scalars: slot i = partial sums for output row yy+i.
#define DECL(i) float A##i = 0.f, B##i = 0.f, C##i = 0.f, D##i = 0.f, E##i = 0.f
// New h-row contributes to slot i with weight w[10-i].
#define ACCI(i) do { const float wj_ = wg(10 - (i));            \
    A##i = fmaf(wj_, hm1,  A##i);                               \
    B##i = fmaf(wj_, hm2,  B##i);                               \
    C##i = fmaf(wj_, hm11, C##i);                               \
    D##i = fmaf(wj_, hm22, D##i);                               \
    E##i = fmaf(wj_, hm12, E##i); } while (0)
#define SHIFT(i, j) A##i = A##j; B##i = B##j; C##i = C##j; D##i = D##j; E##i = E##j

__global__ __launch_bounds__(256, 3) void ssim_kernel(const float* __restrict__ img1,
                                                      const float* __restrict__ img2,
                                                      float* __restrict__ out) {
    __shared__ __align__(16) float sa[4][80];   // 75 used per wave, stride-1
    __shared__ __align__(16) float sb[4][80];
    __shared__ float wsum[4];

    const int tid  = threadIdx.x;
    const int lane = tid & 63;
    const int wv   = tid >> 6;

    const int wid   = blockIdx.x * 4 + wv;     // 0..3071
    const int plane = wid >> 6;
    const int rem   = wid & 63;
    const int strip = rem & 7;
    const int chunk = rem >> 3;
    const int y0 = chunk * CH_H;
    const int c0 = strip * 64;

    // sa[i] <-> img1 col c0-5+i, sb likewise for img2 (i = 0..74).
    const int  colg  = c0 - 5 + lane;          // only <0 can be OOB (max 507)
    const bool colOk = (colg >= 0);
    const int  colC  = colOk ? colg : 0;
    const int  colg2  = c0 + 59 + lane;        // halo cols, lanes 0..10
    const bool colOk2 = (lane < 11) && (colg2 < W_);
    const int  col2C  = colOk2 ? colg2 : 0;

    const size_t pb = (size_t)plane * HW;
    const float* __restrict__ p1  = img1 + pb + colC;
    const float* __restrict__ p2  = img2 + pb + colC;
    const float* __restrict__ p1b = img1 + pb + col2C;
    const float* __restrict__ p2b = img2 + pb + col2C;

    float* s1 = sa[wv];
    float* s2 = sb[wv];

    DECL(0); DECL(1); DECL(2); DECL(3); DECL(4); DECL(5);
    DECL(6); DECL(7); DECL(8); DECL(9); DECL(10);
    float lsum = 0.0f;

    // Preload first h-row (r = y0 - 5; zero if OOB -> matches zero padding).
    float cv1, cv2, cv1b, cv2b;
    {
        int r = y0 - 5;
        bool rok = (unsigned)r < (unsigned)H_;
        size_t off = (size_t)(rok ? r : 0) * W_;
        cv1  = (rok && colOk)  ? p1[off]  : 0.0f;
        cv2  = (rok && colOk)  ? p2[off]  : 0.0f;
        cv1b = (rok && colOk2) ? p1b[off] : 0.0f;
        cv2b = (rok && colOk2) ? p2b[off] : 0.0f;
    }

#pragma unroll 2
    for (int step = 0; step < 74; ++step) {
        const int yy = step - 10;              // output row retired this step

        // 1. Stage current h-row's raw pixels (75 cols per image).
        s1[lane] = cv1;
        s2[lane] = cv2;
        if (lane < 11) { s1[64 + lane] = cv1b; s2[64 + lane] = cv2b; }
        __asm__ __volatile__("" ::: "memory");   // writes complete before reads

        // 2. Prefetch next h-row (r = y0 + yy + 6); independent of this step.
        {
            int r = y0 + yy + 6;
            bool rok = (unsigned)r < (unsigned)H_;
            size_t off = (size_t)(rok ? r : 0) * W_;
            cv1  = (rok && colOk)  ? p1[off]  : 0.0f;
            cv2  = (rok && colOk)  ? p2[off]  : 0.0f;
            cv1b = (rok && colOk2) ? p1b[off] : 0.0f;
            cv2b = (rok && colOk2) ? p2b[off] : 0.0f;
        }

        // 3. Horizontal 11-tap for this lane's output col (c0 + lane).
        float hm1 = 0.f, hm2 = 0.f, hm11 = 0.f, hm22 = 0.f, hm12 = 0.f;
#pragma unroll
        for (int k = 0; k < 11; ++k) {
            float a  = s1[lane + k];
            float b  = s2[lane + k];
            float wk = wg(k);
            float t1 = wk * a;
            float t2 = wk * b;
            hm1  += t1;
            hm2  += t2;
            hm11 = fmaf(t1, a, hm11);
            hm22 = fmaf(t2, b, hm22);
            hm12 = fmaf(t1, b, hm12);
        }
        __asm__ __volatile__("" ::: "memory");   // next iter's writes stay after reads

        // 4. Accumulate into the 11 in-flight output rows.
        ACCI(0); ACCI(1); ACCI(2); ACCI(3); ACCI(4); ACCI(5);
        ACCI(6); ACCI(7); ACCI(8); ACCI(9); ACCI(10);

        // 5. Retire output row yy (slot 0 has all 11 vertical taps).
        if (yy >= 0) lsum += ssim_retire(A0, B0, C0, D0, E0);

        // 6. Shift the register ring (pure SSA renames).
        SHIFT(0, 1); SHIFT(1, 2); SHIFT(2, 3); SHIFT(3, 4); SHIFT(4, 5);
        SHIFT(5, 6); SHIFT(6, 7); SHIFT(7, 8); SHIFT(8, 9); SHIFT(9, 10);
        A10 = 0.f; B10 = 0.f; C10 = 0.f; D10 = 0.f; E10 = 0.f;
    }

    // Reduction: wave shuffle -> LDS -> one atomic per block.
#pragma unroll
    for (int off = 32; off > 0; off >>= 1) lsum += __shfl_down(lsum, off);
    if (lane == 0) wsum[wv] = lsum;
    __syncthreads();
    if (tid == 0) {
        float bs = wsum[0] + wsum[1] + wsum[2] + wsum[3];
        atomicAdd(out, bs * (0.5f / (float)NPIX));
    }
}

extern "C" void kernel_launch(void* const* d_in, const int* in_sizes, int n_in,
                              void* d_out, int out_size, void* d_ws, size_t ws_size,
                              hipStream_t stream) {
    const float* img1 = (const float*)d_in[0];
    const float* img2 = (const float*)d_in[1];
    float* out = (float*)d_out;

    hipMemsetAsync(out, 0, sizeof(float), stream);

    ssim_kernel<<<dim3(8 * 8 * BATCH * CHAN / 4), 256, 0, stream>>>(img1, img2, out);
}

// Round 7
// 154.951 us; speedup vs baseline: 5.5924x; 1.0430x over previous
//
#include <hip/hip_runtime.h>

// SSIM loss v7: v6's row-streaming / 55-named-scalar shift register, with the
// (img1,img2) pair packed into <2 x float> so the backend emits packed-FP32
// VOP3P ops (v_pk_fma_f32 etc., full-rate on gfx950). Per h-tap: 4 VALU
// (pk_mul, pk_add, pk_fma, scalar fma) vs 7 scalar; vertical: 3 inst/slot
// vs 5. LDS staged interleaved -> 11 ds_read_b64/step vs 22 ds_read_b32.
// Grid: 8 strips x 8 chunks x 48 planes = 3072 waves = 768 blocks = 3/CU.

#define BATCH  16
#define CHAN   3
#define H_     512
#define W_     512
#define HW     (H_ * W_)
#define CH_H   64
#define NPIX   ((long)BATCH*CHAN*H_*W_)

// Normalized 11-tap Gaussian, sigma=1.5 (constants gave absmax 0 in v1/v2/v6).
#define GW0 0.0010284f
#define GW1 0.0075988f
#define GW2 0.0360008f
#define GW3 0.1093554f
#define GW4 0.2130056f
#define GW5 0.2660117f

typedef float v2 __attribute__((ext_vector_type(2)));

__device__ __forceinline__ float wg(int k) {  // k literal -> folds to constant
    return (k == 0 || k == 10) ? GW0
         : (k == 1 || k == 9)  ? GW1
         : (k == 2 || k == 8)  ? GW2
         : (k == 3 || k == 7)  ? GW3
         : (k == 4 || k == 6)  ? GW4 : GW5;
}

__device__ __forceinline__ v2 pfma(v2 a, v2 b, v2 c) {
#if __has_builtin(__builtin_elementwise_fma)
    return __builtin_elementwise_fma(a, b, c);
#else
    v2 r; r.x = fmaf(a.x, b.x, c.x); r.y = fmaf(a.y, b.y, c.y); return r;
#endif
}
__device__ __forceinline__ v2 psfma(float s, v2 b, v2 c) {  // (s,s)*b + c
    v2 sv; sv.x = s; sv.y = s;
    return pfma(sv, b, c);
}

__device__ __forceinline__ float ssim_retire(float mu1, float mu2,
                                             float x11, float x22, float x12) {
    const float c1 = 1.0e-4f;
    const float c2 = 9.0e-4f;
    float mu1s = mu1 * mu1;
    float mu2s = mu2 * mu2;
    float m12  = mu1 * mu2;
    float num  = (2.0f * m12 + c1) * (2.0f * (x12 - m12) + c2);
    float den  = (mu1s + mu2s + c1) * ((x11 - mu1s) + (x22 - mu2s) + c2);
    float l = 1.0f - num / den;
    return fminf(fmaxf(l, 0.0f), 1.0f);
}

// Slot i state: P=(mu1,mu2) packed, Q=(x11,x22) packed, E=x12 scalar.
#define DECL(i) v2 P##i = {0.f, 0.f}, Q##i = {0.f, 0.f}; float E##i = 0.f
#define ACCI(i) do { const float wj_ = wg(10 - (i));             \
    P##i = psfma(wj_, hmm, P##i);                                \
    Q##i = psfma(wj_, hss, Q##i);                                \
    E##i = fmaf(wj_, hm12, E##i); } while (0)
#define SHIFT(i, j) P##i = P##j; Q##i = Q##j; E##i = E##j

__global__ __launch_bounds__(256, 3) void ssim_kernel(const float* __restrict__ img1,
                                                      const float* __restrict__ img2,
                                                      float* __restrict__ out) {
    __shared__ __align__(16) v2 sp[4][80];   // interleaved (img1,img2), 75 used
    __shared__ float wsum[4];

    const int tid  = threadIdx.x;
    const int lane = tid & 63;
    const int wv   = tid >> 6;

    const int wid   = blockIdx.x * 4 + wv;     // 0..3071
    const int plane = wid >> 6;
    const int rem   = wid & 63;
    const int strip = rem & 7;
    const int chunk = rem >> 3;
    const int y0 = chunk * CH_H;
    const int c0 = strip * 64;

    // sp[i] <-> cols c0-5+i of (img1, img2), i = 0..74.
    const int  colg  = c0 - 5 + lane;          // only <0 can be OOB (max 507)
    const bool colOk = (colg >= 0);
    const int  colC  = colOk ? colg : 0;
    const int  colg2  = c0 + 59 + lane;        // halo cols, lanes 0..10
    const bool colOk2 = (lane < 11) && (colg2 < W_);
    const int  col2C  = colOk2 ? colg2 : 0;

    const size_t pb = (size_t)plane * HW;
    const float* __restrict__ p1  = img1 + pb + colC;
    const float* __restrict__ p2  = img2 + pb + colC;
    const float* __restrict__ p1b = img1 + pb + col2C;
    const float* __restrict__ p2b = img2 + pb + col2C;

    v2* st = sp[wv];

    DECL(0); DECL(1); DECL(2); DECL(3); DECL(4); DECL(5);
    DECL(6); DECL(7); DECL(8); DECL(9); DECL(10);
    float lsum = 0.0f;

    // Preload first h-row (r = y0 - 5; zero if OOB -> matches zero padding).
    float cv1, cv2, cv1b, cv2b;
    {
        int r = y0 - 5;
        bool rok = (unsigned)r < (unsigned)H_;
        size_t off = (size_t)(rok ? r : 0) * W_;
        cv1  = (rok && colOk)  ? p1[off]  : 0.0f;
        cv2  = (rok && colOk)  ? p2[off]  : 0.0f;
        cv1b = (rok && colOk2) ? p1b[off] : 0.0f;
        cv2b = (rok && colOk2) ? p2b[off] : 0.0f;
    }

#pragma unroll 2
    for (int step = 0; step < 74; ++step) {
        const int yy = step - 10;              // output row retired this step

        // 1. Stage current h-row (75 interleaved col-pairs).
        {
            v2 v; v.x = cv1; v.y = cv2;
            st[lane] = v;
            if (lane < 11) { v2 vb; vb.x = cv1b; vb.y = cv2b; st[64 + lane] = vb; }
        }
        __asm__ __volatile__("" ::: "memory");   // writes complete before reads

        // 2. Prefetch next h-row (r = y0 + yy + 6); independent of this step.
        {
            int r = y0 + yy + 6;
            bool rok = (unsigned)r < (unsigned)H_;
            size_t off = (size_t)(rok ? r : 0) * W_;
            cv1  = (rok && colOk)  ? p1[off]  : 0.0f;
            cv2  = (rok && colOk)  ? p2[off]  : 0.0f;
            cv1b = (rok && colOk2) ? p1b[off] : 0.0f;
            cv2b = (rok && colOk2) ? p2b[off] : 0.0f;
        }

        // 3. Horizontal 11-tap, packed: hmm=(m1,m2), hss=(m11,m22), hm12.
        v2 hmm = {0.f, 0.f}, hss = {0.f, 0.f};
        float hm12 = 0.f;
#pragma unroll
        for (int k = 0; k < 11; ++k) {
            v2 ab = st[lane + k];              // ds_read_b64
            float wk = wg(k);
            v2 t = ab;
            t.x *= wk; t.y *= wk;              // pk_mul (t1,t2)
            hmm += t;                          // pk_add
            hss = pfma(t, ab, hss);            // pk_fma -> (m11,m22)
            hm12 = fmaf(t.x, ab.y, hm12);      // scalar cross term
        }
        __asm__ __volatile__("" ::: "memory");   // next iter's writes stay after reads

        // 4. Accumulate into the 11 in-flight output rows.
        ACCI(0); ACCI(1); ACCI(2); ACCI(3); ACCI(4); ACCI(5);
        ACCI(6); ACCI(7); ACCI(8); ACCI(9); ACCI(10);

        // 5. Retire output row yy (slot 0 complete).
        if (yy >= 0) lsum += ssim_retire(P0.x, P0.y, Q0.x, Q0.y, E0);

        // 6. Shift the register ring (pure SSA renames; unroll-2 elides half).
        SHIFT(0, 1); SHIFT(1, 2); SHIFT(2, 3); SHIFT(3, 4); SHIFT(4, 5);
        SHIFT(5, 6); SHIFT(6, 7); SHIFT(7, 8); SHIFT(8, 9); SHIFT(9, 10);
        P10 = (v2){0.f, 0.f}; Q10 = (v2){0.f, 0.f}; E10 = 0.f;
    }

    // Reduction: wave shuffle -> LDS -> one atomic per block.
#pragma unroll
    for (int off = 32; off > 0; off >>= 1) lsum += __shfl_down(lsum, off);
    if (lane == 0) wsum[wv] = lsum;
    __syncthreads();
    if (tid == 0) {
        float bs = wsum[0] + wsum[1] + wsum[2] + wsum[3];
        atomicAdd(out, bs * (0.5f / (float)NPIX));
    }
}

extern "C" void kernel_launch(void* const* d_in, const int* in_sizes, int n_in,
                              void* d_out, int out_size, void* d_ws, size_t ws_size,
                              hipStream_t stream) {
    const float* img1 = (const float*)d_in[0];
    const float* img2 = (const float*)d_in[1];
    float* out = (float*)d_out;

    hipMemsetAsync(out, 0, sizeof(float), stream);

    ssim_kernel<<<dim3(8 * 8 * BATCH * CHAN / 4), 256, 0, stream>>>(img1, img2, out);
}